// Round 2
// baseline (99.231 us; speedup 1.0000x reference)
//
#include <hip/hip_runtime.h>
#include <math.h>

// Problem constants
#define BB   32
#define CC   256
#define HH   56
#define WW   56
#define HID  512
#define RNK  8
#define HWN  (HH * WW)     // 3136
#define HW4  (HWN / 4)     // 784 float4 per (b,c) plane

// ---------------------------------------------------------------------------
// Kernel 1: global average pool.  One 256-thread block per (b,c) row.
// Each row is 3136 contiguous floats = 784 float4.  Wave shuffle reduce +
// LDS across the 4 waves.
// ---------------------------------------------------------------------------
__global__ __launch_bounds__(256) void pool_kernel(const float* __restrict__ x,
                                                   float* __restrict__ y) {
    const int bc  = blockIdx.x;       // 0 .. B*C-1
    const int tid = threadIdx.x;      // 0 .. 255
    const float4* xp = reinterpret_cast<const float4*>(x) + (size_t)bc * HW4;

    float s = 0.0f;
    for (int p = tid; p < HW4; p += 256) {
        float4 v = xp[p];
        s += (v.x + v.y) + (v.z + v.w);
    }
    // wave(64) reduction
    #pragma unroll
    for (int off = 32; off > 0; off >>= 1) s += __shfl_down(s, off, 64);

    __shared__ float ls[4];
    const int wave = tid >> 6;
    if ((tid & 63) == 0) ls[wave] = s;
    __syncthreads();
    if (tid == 0) {
        float t = (ls[0] + ls[1]) + (ls[2] + ls[3]);
        y[bc] = t * (1.0f / (float)HWN);
    }
}

// ---------------------------------------------------------------------------
// Kernel 2: per-batch MLP (exact GELU) + low-rank A*B + sigmoid -> attn map.
// One 256-thread block per batch element. All intermediates live in LDS.
// ---------------------------------------------------------------------------
__device__ __forceinline__ float gelu_exact(float v) {
    return 0.5f * v * (1.0f + erff(v * 0.70710678118654752f));
}

__global__ __launch_bounds__(256) void mlp_kernel(const float* __restrict__ y,
                                                  const float* __restrict__ w1,
                                                  const float* __restrict__ w2,
                                                  const float* __restrict__ wA,
                                                  const float* __restrict__ wB,
                                                  float* __restrict__ attn) {
    const int b   = blockIdx.x;       // 0 .. B-1
    const int tid = threadIdx.x;      // 0 .. 255

    __shared__ float y_s[CC];
    __shared__ float h_s[HID];
    __shared__ float yp_s[CC];
    __shared__ float a_s[HH * RNK];    // 448
    __shared__ float bb_s[RNK * WW];   // 448

    y_s[tid] = y[b * CC + tid];
    __syncthreads();

    // h = gelu(y @ w1.T)   (HID outputs, dot length CC)
    for (int j = tid; j < HID; j += 256) {
        const float4* wr = reinterpret_cast<const float4*>(w1 + (size_t)j * CC);
        float d = 0.0f;
        #pragma unroll 4
        for (int c4 = 0; c4 < CC / 4; ++c4) {
            float4 wv = wr[c4];
            d += wv.x * y_s[c4 * 4 + 0] + wv.y * y_s[c4 * 4 + 1]
               + wv.z * y_s[c4 * 4 + 2] + wv.w * y_s[c4 * 4 + 3];
        }
        h_s[j] = gelu_exact(d);
    }
    __syncthreads();

    // y' = gelu(h @ w2.T)  (CC outputs, dot length HID)
    {
        const int i = tid;
        const float4* wr = reinterpret_cast<const float4*>(w2 + (size_t)i * HID);
        float d = 0.0f;
        #pragma unroll 4
        for (int c4 = 0; c4 < HID / 4; ++c4) {
            float4 wv = wr[c4];
            d += wv.x * h_s[c4 * 4 + 0] + wv.y * h_s[c4 * 4 + 1]
               + wv.z * h_s[c4 * 4 + 2] + wv.w * h_s[c4 * 4 + 3];
        }
        yp_s[i] = gelu_exact(d);
    }
    __syncthreads();

    // A = y' @ wA.T  -> a_s[h*RNK + r]   (448 outputs, dot length CC)
    for (int p = tid; p < HH * RNK; p += 256) {
        const float4* wr = reinterpret_cast<const float4*>(wA + (size_t)p * CC);
        float d = 0.0f;
        #pragma unroll 4
        for (int c4 = 0; c4 < CC / 4; ++c4) {
            float4 wv = wr[c4];
            d += wv.x * yp_s[c4 * 4 + 0] + wv.y * yp_s[c4 * 4 + 1]
               + wv.z * yp_s[c4 * 4 + 2] + wv.w * yp_s[c4 * 4 + 3];
        }
        a_s[p] = d;
    }
    // Bm = y' @ wB.T -> bb_s[r*WW + w]   (448 outputs, dot length CC)
    for (int q = tid; q < RNK * WW; q += 256) {
        const float4* wr = reinterpret_cast<const float4*>(wB + (size_t)q * CC);
        float d = 0.0f;
        #pragma unroll 4
        for (int c4 = 0; c4 < CC / 4; ++c4) {
            float4 wv = wr[c4];
            d += wv.x * yp_s[c4 * 4 + 0] + wv.y * yp_s[c4 * 4 + 1]
               + wv.z * yp_s[c4 * 4 + 2] + wv.w * yp_s[c4 * 4 + 3];
        }
        bb_s[q] = d;
    }
    __syncthreads();

    // M[i][j] = sum_r A[i][r] * Bm[r][j];  attn = sigmoid(M)
    for (int p = tid; p < HWN; p += 256) {
        const int i = p / WW;
        const int j = p - i * WW;
        float m = 0.0f;
        #pragma unroll
        for (int r = 0; r < RNK; ++r) m += a_s[i * RNK + r] * bb_s[r * WW + j];
        attn[(size_t)b * HWN + p] = 1.0f / (1.0f + expf(-m));
    }
}

// ---------------------------------------------------------------------------
// Kernel 3: broadcast attn (B,H,W) across the C channel dim -> out (B,C,H,W).
// Pure bandwidth: grid-stride float4 stores; attn reads are L1/L2 resident
// (401 KB total).
// ---------------------------------------------------------------------------
__global__ __launch_bounds__(256) void bcast_kernel(const float* __restrict__ attn,
                                                    float4* __restrict__ out) {
    const unsigned total  = (unsigned)BB * CC * HW4;   // 6,422,528 float4
    const unsigned stride = gridDim.x * blockDim.x;
    const float4* ap = reinterpret_cast<const float4*>(attn);
    for (unsigned idx = blockIdx.x * blockDim.x + threadIdx.x; idx < total;
         idx += stride) {
        const unsigned b = idx / (CC * HW4);   // plane index in batch
        const unsigned p = idx % HW4;          // float4 offset within plane
        out[idx] = ap[b * HW4 + p];
    }
}

// ---------------------------------------------------------------------------
extern "C" void kernel_launch(void* const* d_in, const int* in_sizes, int n_in,
                              void* d_out, int out_size, void* d_ws, size_t ws_size,
                              hipStream_t stream) {
    const float* x  = (const float*)d_in[0];
    const float* w1 = (const float*)d_in[1];
    const float* w2 = (const float*)d_in[2];
    const float* wA = (const float*)d_in[3];
    const float* wB = (const float*)d_in[4];
    float* out = (float*)d_out;

    // workspace layout: y (B*C floats) | attn (B*H*W floats)
    float* y    = (float*)d_ws;
    float* attn = (float*)d_ws + (BB * CC);

    pool_kernel<<<BB * CC, 256, 0, stream>>>(x, y);
    mlp_kernel<<<BB, 256, 0, stream>>>(y, w1, w2, wA, wB, attn);
    bcast_kernel<<<2048, 256, 0, stream>>>(attn, reinterpret_cast<float4*>(out));
}

// Round 3
// 99.024 us; speedup vs baseline: 1.0021x; 1.0021x over previous
//
#include <hip/hip_runtime.h>
#include <math.h>

// Problem constants
#define BB   32
#define CC   256
#define HH   56
#define WW   56
#define HID  512
#define RNK  8
#define HWN  (HH * WW)     // 3136
#define HW4  (HWN / 4)     // 784 float4 per (b,c) plane

// ---------------------------------------------------------------------------
// Kernel 1: global average pool.  One 256-thread block per (b,c) row.
// ---------------------------------------------------------------------------
__global__ __launch_bounds__(256) void pool_kernel(const float* __restrict__ x,
                                                   float* __restrict__ y) {
    const int bc  = blockIdx.x;       // 0 .. B*C-1
    const int tid = threadIdx.x;      // 0 .. 255
    const float4* xp = reinterpret_cast<const float4*>(x) + (size_t)bc * HW4;

    float s = 0.0f;
    for (int p = tid; p < HW4; p += 256) {
        float4 v = xp[p];
        s += (v.x + v.y) + (v.z + v.w);
    }
    #pragma unroll
    for (int off = 32; off > 0; off >>= 1) s += __shfl_down(s, off, 64);

    __shared__ float ls[4];
    const int wave = tid >> 6;
    if ((tid & 63) == 0) ls[wave] = s;
    __syncthreads();
    if (tid == 0) {
        float t = (ls[0] + ls[1]) + (ls[2] + ls[3]);
        y[bc] = t * (1.0f / (float)HWN);
    }
}

// ---------------------------------------------------------------------------
// Kernel 2: per-batch MLP + low-rank A*B + sigmoid.
// One 1024-thread block (16 waves) per batch element.
// Wave-per-output GEMV: the 64 lanes of a wave cooperatively read one weight
// row (coalesced float4: lane l covers columns 4l..4l+3), dot against the
// activation vector (held as a per-lane float4 register), then butterfly
// shuffle-reduce.  This replaces the round-2 layout where each THREAD read
// its own 1KB-strided row (uncoalesced, latency-bound, 77.7us).
// ---------------------------------------------------------------------------
__device__ __forceinline__ float gelu_exact(float v) {
    return 0.5f * v * (1.0f + erff(v * 0.70710678118654752f));
}

__device__ __forceinline__ float dot4(float4 a, float4 b) {
    return a.x * b.x + a.y * b.y + a.z * b.z + a.w * b.w;
}

__device__ __forceinline__ float wave_reduce(float d) {
    #pragma unroll
    for (int m = 32; m > 0; m >>= 1) d += __shfl_xor(d, m, 64);
    return d;
}

__global__ __launch_bounds__(1024) void mlp_kernel(const float* __restrict__ y,
                                                   const float* __restrict__ w1,
                                                   const float* __restrict__ w2,
                                                   const float* __restrict__ wA,
                                                   const float* __restrict__ wB,
                                                   float* __restrict__ attn) {
    const int b    = blockIdx.x;      // 0 .. B-1
    const int tid  = threadIdx.x;     // 0 .. 1023
    const int lane = tid & 63;
    const int wv   = tid >> 6;        // 0 .. 15

    __shared__ float y_s[CC];
    __shared__ float h_s[HID];
    __shared__ float yp_s[CC];
    __shared__ float a_s[HH * RNK];    // 448
    __shared__ float bb_s[RNK * WW];   // 448

    if (tid < CC) y_s[tid] = y[b * CC + tid];
    __syncthreads();

    // Stage 1: h = gelu(y @ w1.T)   (512 rows, dot length 256)
    {
        const float4 yv = reinterpret_cast<const float4*>(y_s)[lane];
        for (int j = wv; j < HID; j += 16) {
            const float4 w = reinterpret_cast<const float4*>(w1 + (size_t)j * CC)[lane];
            float d = wave_reduce(dot4(w, yv));
            if (lane == 0) h_s[j] = gelu_exact(d);
        }
    }
    __syncthreads();

    // Stage 2: y' = gelu(h @ w2.T)  (256 rows, dot length 512)
    {
        const float4 h0 = reinterpret_cast<const float4*>(h_s)[lane];
        const float4 h1 = reinterpret_cast<const float4*>(h_s)[lane + 64];
        for (int i = wv; i < CC; i += 16) {
            const float4* wr = reinterpret_cast<const float4*>(w2 + (size_t)i * HID);
            float d = wave_reduce(dot4(wr[lane], h0) + dot4(wr[lane + 64], h1));
            if (lane == 0) yp_s[i] = gelu_exact(d);
        }
    }
    __syncthreads();

    // Stage 3: A = y'@wA.T (448 rows), Bm = y'@wB.T (448 rows), dot length 256
    {
        const float4 pv = reinterpret_cast<const float4*>(yp_s)[lane];
        for (int p = wv; p < HH * RNK; p += 16) {
            const float4 w = reinterpret_cast<const float4*>(wA + (size_t)p * CC)[lane];
            float d = wave_reduce(dot4(w, pv));
            if (lane == 0) a_s[p] = d;
        }
        for (int q = wv; q < RNK * WW; q += 16) {
            const float4 w = reinterpret_cast<const float4*>(wB + (size_t)q * CC)[lane];
            float d = wave_reduce(dot4(w, pv));
            if (lane == 0) bb_s[q] = d;
        }
    }
    __syncthreads();

    // Stage 4: M[i][j] = sum_r A[i][r]*Bm[r][j]; attn = sigmoid(M)
    for (int p = tid; p < HWN; p += 1024) {
        const int i = p / WW;
        const int j = p - i * WW;
        float m = 0.0f;
        #pragma unroll
        for (int r = 0; r < RNK; ++r) m += a_s[i * RNK + r] * bb_s[r * WW + j];
        attn[(size_t)b * HWN + p] = 1.0f / (1.0f + expf(-m));
    }
}

// ---------------------------------------------------------------------------
// Kernel 3: broadcast attn (B,H,W) across C -> out (B,C,H,W).
// ---------------------------------------------------------------------------
__global__ __launch_bounds__(256) void bcast_kernel(const float* __restrict__ attn,
                                                    float4* __restrict__ out) {
    const unsigned total  = (unsigned)BB * CC * HW4;   // 6,422,528 float4
    const unsigned stride = gridDim.x * blockDim.x;
    const float4* ap = reinterpret_cast<const float4*>(attn);
    for (unsigned idx = blockIdx.x * blockDim.x + threadIdx.x; idx < total;
         idx += stride) {
        const unsigned b = idx / (CC * HW4);   // batch index
        const unsigned p = idx % HW4;          // float4 offset within plane
        out[idx] = ap[b * HW4 + p];
    }
}

// ---------------------------------------------------------------------------
extern "C" void kernel_launch(void* const* d_in, const int* in_sizes, int n_in,
                              void* d_out, int out_size, void* d_ws, size_t ws_size,
                              hipStream_t stream) {
    const float* x  = (const float*)d_in[0];
    const float* w1 = (const float*)d_in[1];
    const float* w2 = (const float*)d_in[2];
    const float* wA = (const float*)d_in[3];
    const float* wB = (const float*)d_in[4];
    float* out = (float*)d_out;

    // workspace layout: y (B*C floats) | attn (B*H*W floats)
    float* y    = (float*)d_ws;
    float* attn = (float*)d_ws + (BB * CC);

    pool_kernel<<<BB * CC, 256, 0, stream>>>(x, y);
    mlp_kernel<<<BB, 1024, 0, stream>>>(y, w1, w2, wA, wB, attn);
    bcast_kernel<<<2048, 256, 0, stream>>>(attn, reinterpret_cast<float4*>(out));
}

// Round 4
// 52.409 us; speedup vs baseline: 1.8934x; 1.8895x over previous
//
#include <hip/hip_runtime.h>
#include <math.h>

// Problem constants
#define BB   32
#define CC   256
#define HH   56
#define WW   56
#define HID  512
#define RNK  8
#define HWN  (HH * WW)     // 3136
#define HW4  (HWN / 4)     // 784 float4 per (b,c) plane

__device__ __forceinline__ float gelu_exact(float v) {
    return 0.5f * v * (1.0f + erff(v * 0.70710678118654752f));
}
__device__ __forceinline__ float dot4(float4 a, float4 b) {
    return a.x * b.x + a.y * b.y + a.z * b.z + a.w * b.w;
}
__device__ __forceinline__ float wave_reduce(float d) {
    #pragma unroll
    for (int m = 32; m > 0; m >>= 1) d += __shfl_xor(d, m, 64);
    return d;
}

// ---------------------------------------------------------------------------
// Kernel 1: global average pool.  One 256-thread block per (b,c) plane.
// 103 MB read -> HBM/L3-bound, ~16 us floor.
// ---------------------------------------------------------------------------
__global__ __launch_bounds__(256) void pool_kernel(const float* __restrict__ x,
                                                   float* __restrict__ y) {
    const int bc  = blockIdx.x;
    const int tid = threadIdx.x;
    const float4* xp = reinterpret_cast<const float4*>(x) + (size_t)bc * HW4;

    float s = 0.0f;
    for (int p = tid; p < HW4; p += 256) {
        float4 v = xp[p];
        s += (v.x + v.y) + (v.z + v.w);
    }
    #pragma unroll
    for (int off = 32; off > 0; off >>= 1) s += __shfl_down(s, off, 64);

    __shared__ float ls[4];
    const int wave = tid >> 6;
    if ((tid & 63) == 0) ls[wave] = s;
    __syncthreads();
    if (tid == 0) {
        float t = (ls[0] + ls[1]) + (ls[2] + ls[3]);
        y[bc] = t * (1.0f / (float)HWN);
    }
}

// ---------------------------------------------------------------------------
// Wave-per-output GEMV: out[b][j] = act(dot(in[b][:K], W[j][:K])).
// One wave per output element -> B*J waves total; latency of the 6-step
// shuffle chain is hidden by thousands of concurrent waves (the round-3
// version ran only 32 blocks and serialized ~100 rows per wave).
// ---------------------------------------------------------------------------
template <int K, int J, bool GELU>
__global__ __launch_bounds__(256) void gemv_kernel(const float* __restrict__ in,
                                                   const float* __restrict__ W,
                                                   float* __restrict__ out) {
    const int lane = threadIdx.x & 63;
    const int wid  = (blockIdx.x * 256 + threadIdx.x) >> 6;  // global wave id
    const int b = wid / J;
    const int j = wid - b * J;
    const float4* wr = reinterpret_cast<const float4*>(W  + (size_t)j * K);
    const float4* ir = reinterpret_cast<const float4*>(in + (size_t)b * K);
    float d;
    if constexpr (K == 256) {
        d = dot4(wr[lane], ir[lane]);
    } else {  // K == 512
        d = dot4(wr[lane], ir[lane]) + dot4(wr[lane + 64], ir[lane + 64]);
    }
    d = wave_reduce(d);
    if (lane == 0) out[(size_t)b * J + j] = GELU ? gelu_exact(d) : d;
}

// Stage 3: A = y'@wA.T and Bm = y'@wB.T fused into one launch.
// j in [0,448) -> wA row j; j in [448,896) -> wB row j-448.
__global__ __launch_bounds__(256) void gemv_ab_kernel(const float* __restrict__ yp,
                                                      const float* __restrict__ wA,
                                                      const float* __restrict__ wB,
                                                      float* __restrict__ ab) {
    const int lane = threadIdx.x & 63;
    const int wid  = (blockIdx.x * 256 + threadIdx.x) >> 6;
    const int b = wid / 896;
    const int j = wid - b * 896;
    const float* W = (j < 448) ? (wA + (size_t)j * CC)
                               : (wB + (size_t)(j - 448) * CC);
    const float4* wr = reinterpret_cast<const float4*>(W);
    const float4* ir = reinterpret_cast<const float4*>(yp + (size_t)b * CC);
    float d = wave_reduce(dot4(wr[lane], ir[lane]));
    if (lane == 0) ab[(size_t)b * 896 + j] = d;
}

// Stage 4: attn[b][p] = sigmoid(sum_r A[b][i][r] * Bm[b][r][j]), thread/elem.
__global__ __launch_bounds__(256) void attnmap_kernel(const float* __restrict__ ab,
                                                      float* __restrict__ attn) {
    const int idx = blockIdx.x * 256 + threadIdx.x;   // 0 .. B*HWN-1
    const int b = idx / HWN;
    const int p = idx - b * HWN;
    const int i = p / WW;
    const int j = p - i * WW;
    const float* A  = ab + (size_t)b * 896 + i * RNK;
    const float* Bm = ab + (size_t)b * 896 + 448 + j;
    float m = 0.0f;
    #pragma unroll
    for (int r = 0; r < RNK; ++r) m += A[r] * Bm[r * WW];
    attn[idx] = 1.0f / (1.0f + expf(-m));
}

// ---------------------------------------------------------------------------
// Kernel 3: broadcast attn (B,H,W) across C -> out (B,C,H,W).  Write-bound.
// ---------------------------------------------------------------------------
__global__ __launch_bounds__(256) void bcast_kernel(const float* __restrict__ attn,
                                                    float4* __restrict__ out) {
    const unsigned total  = (unsigned)BB * CC * HW4;   // 6,422,528 float4
    const unsigned stride = gridDim.x * blockDim.x;
    const float4* ap = reinterpret_cast<const float4*>(attn);
    for (unsigned idx = blockIdx.x * blockDim.x + threadIdx.x; idx < total;
         idx += stride) {
        const unsigned b = idx / (CC * HW4);
        const unsigned p = idx % HW4;
        out[idx] = ap[b * HW4 + p];
    }
}

// ---------------------------------------------------------------------------
extern "C" void kernel_launch(void* const* d_in, const int* in_sizes, int n_in,
                              void* d_out, int out_size, void* d_ws, size_t ws_size,
                              hipStream_t stream) {
    const float* x  = (const float*)d_in[0];
    const float* w1 = (const float*)d_in[1];
    const float* w2 = (const float*)d_in[2];
    const float* wA = (const float*)d_in[3];
    const float* wB = (const float*)d_in[4];
    float* out = (float*)d_out;

    // ws layout (floats): y[B*C] | h[B*HID] | yp[B*C] | ab[B*896] | attn[B*HWN]
    float* y    = (float*)d_ws;
    float* h    = y  + BB * CC;         // 8192
    float* yp   = h  + BB * HID;        // 16384
    float* ab   = yp + BB * CC;         // 8192
    float* attn = ab + BB * 896;        // 28672  (total 161792 floats = 647 KB)

    pool_kernel<<<BB * CC, 256, 0, stream>>>(x, y);
    gemv_kernel<CC, HID, true><<<(BB * HID) / 4, 256, 0, stream>>>(y, w1, h);
    gemv_kernel<HID, CC, true><<<(BB * CC) / 4, 256, 0, stream>>>(h, w2, yp);
    gemv_ab_kernel<<<(BB * 896) / 4, 256, 0, stream>>>(yp, wA, wB, ab);
    attnmap_kernel<<<(BB * HWN) / 256, 256, 0, stream>>>(ab, attn);
    bcast_kernel<<<2048, 256, 0, stream>>>(attn, reinterpret_cast<float4*>(out));
}